// Round 4
// baseline (286.757 us; speedup 1.0000x reference)
//
#include <hip/hip_runtime.h>

#define WW 1024
#define HH 1024
#define BB 16
#define HWSZ (HH * WW)
#define NBLK (BB * HH)

// ---------------------------------------------------------------------------
// D2(f) = gradient(gradient(f)) along one axis (jnp.gradient semantics):
//   i=0:      (f0 - 2 f1 + f2)/2
//   i=1:      (2 f0 - 3 f1 + f3)/4
//   interior: (f[i-2] - 2 f[i] + f[i+2])/4
//   i=N-2:    (f[N-4] - 3 f[N-2] + 2 f[N-1])/4
//   i=N-1:    (f[N-3] - 2 f[N-2] + f[N-1])/2
// ---------------------------------------------------------------------------

// Compute-only: consumes pre-loaded float4s (load phase is hoisted to the
// kernel body so all global loads issue back-to-back -> max MLP).
__device__ __forceinline__ void lap_compute(const float4 vh, const float4 vhp,
                                            const float4 vhn, const float4 vA,
                                            const float4 vB, int g,
                                            float cA, float cB, float ch,
                                            float out[4]) {
    float vert[4];
    vert[0] = cA * vA.x + cB * vB.x + ch * vh.x;
    vert[1] = cA * vA.y + cB * vB.y + ch * vh.y;
    vert[2] = cA * vA.z + cB * vB.z + ch * vh.z;
    vert[3] = cA * vA.w + cB * vB.w + ch * vh.w;

    // horizontal: window f[4g-2 .. 4g+5]
    float win[8] = {vhp.z, vhp.w, vh.x, vh.y, vh.z, vh.w, vhn.x, vhn.y};
    float hz[4];
#pragma unroll
    for (int p = 0; p < 4; ++p)
        hz[p] = 0.25f * (win[p] - 2.0f * win[p + 2] + win[p + 4]);

    if (g == 0) {                         // columns 0,1
        hz[0] = 0.5f  * (vh.x - 2.0f * vh.y + vh.z);
        hz[1] = 0.25f * (2.0f * vh.x - 3.0f * vh.y + vh.w);
    } else if (g == WW / 4 - 1) {         // columns W-2, W-1
        hz[2] = 0.25f * (vh.x - 3.0f * vh.z + 2.0f * vh.w);
        hz[3] = 0.5f  * (vh.y - 2.0f * vh.z + vh.w);
    }

#pragma unroll
    for (int p = 0; p < 4; ++p) out[p] = vert[p] + hz[p];
}

// USE_ATOMIC=0: deterministic per-block partials. 1: single f64 atomic.
template <int USE_ATOMIC>
__global__ __launch_bounds__(256) void gl2_main(const float* __restrict__ u,
                                                const float* __restrict__ psi,
                                                double* __restrict__ part) {
    // XCD-aware bijective swizzle (gridDim.x = 16384, divisible by 8)
    const int bid  = blockIdx.x;
    const int work = (bid & 7) * (NBLK >> 3) + (bid >> 3);
    const int b = work >> 10;
    const int h = work & 1023;
    const int g = threadIdx.x;

    int rA, rB; float cA, cB, ch;
    if (h == 0)            { rA = 1;      rB = 2;      cA = -1.0f;  cB = 0.5f;   ch = 0.5f;   }
    else if (h == 1)       { rA = 0;      rB = 3;      cA = 0.5f;   cB = 0.25f;  ch = -0.75f; }
    else if (h == HH - 2)  { rA = HH - 4; rB = HH - 1; cA = 0.25f;  cB = 0.5f;   ch = -0.75f; }
    else if (h == HH - 1)  { rA = HH - 3; rB = HH - 2; cA = 0.5f;   cB = -1.0f;  ch = 0.5f;   }
    else                   { rA = h - 2;  rB = h + 2;  cA = 0.25f;  cB = 0.25f;  ch = -0.5f;  }

    const float* ux = u   + ((size_t)b * 2 + 0) * HWSZ;
    const float* uy = u   + ((size_t)b * 2 + 1) * HWSZ;
    const float* pr = psi + ((size_t)b * 2 + 0) * HWSZ;
    const float* pi = psi + ((size_t)b * 2 + 1) * HWSZ;

    const int gp = (g > 0) ? g - 1 : g;
    const int gn = (g < WW / 4 - 1) ? g + 1 : g;

    // ---- LOAD PHASE: 12 independent float4 loads, issued back-to-back ----
    const float4* xrh = (const float4*)(ux + (size_t)h * WW);
    const float4* yrh = (const float4*)(uy + (size_t)h * WW);
    const float4 xh = xrh[g];
    const float4 xp = xrh[gp];
    const float4 xn = xrh[gn];
    const float4 xA = ((const float4*)(ux + (size_t)rA * WW))[g];
    const float4 xB = ((const float4*)(ux + (size_t)rB * WW))[g];
    const float4 yh = yrh[g];
    const float4 yp = yrh[gp];
    const float4 yn = yrh[gn];
    const float4 yA = ((const float4*)(uy + (size_t)rA * WW))[g];
    const float4 yB = ((const float4*)(uy + (size_t)rB * WW))[g];
    const float4 r4 = ((const float4*)(pr + (size_t)h * WW))[g];
    const float4 i4 = ((const float4*)(pi + (size_t)h * WW))[g];
    // Pin the load cluster: nothing moves across this point, so all 12
    // global_load_dwordx4 are outstanding together (one latency, not twelve).
    __builtin_amdgcn_sched_barrier(0);

    // ---- COMPUTE PHASE ----
    float lapx[4], lapy[4];
    lap_compute(xh, xp, xn, xA, xB, g, cA, cB, ch, lapx);
    lap_compute(yh, yp, yn, yA, yB, g, cA, cB, ch, lapy);

    const float rr[4] = {r4.x, r4.y, r4.z, r4.w};
    const float ii[4] = {i4.x, i4.y, i4.z, i4.w};

    float s = 0.0f;
#pragma unroll
    for (int p = 0; p < 4; ++p) {
        const float c   = 1.0f - (rr[p] * rr[p] + ii[p] * ii[p]);   // 1/eps^2 = 1
        const float lap = lapx[p] + lapy[p];
        const float re  = lap + c * rr[p];
        const float im  = c * ii[p];
        s += re * re + im * im;
    }

#pragma unroll
    for (int off = 32; off > 0; off >>= 1) s += __shfl_down(s, off);

    __shared__ float wsum[4];
    const int lane = threadIdx.x & 63;
    const int wv   = threadIdx.x >> 6;
    if (lane == 0) wsum[wv] = s;
    __syncthreads();
    if (threadIdx.x == 0) {
        const double t = (double)(wsum[0] + wsum[1]) + (double)(wsum[2] + wsum[3]);
        if (USE_ATOMIC) atomicAdd(part, t);
        else            part[bid] = t;
    }
}

__global__ void gl2_zero_acc(double* acc) {
    if (threadIdx.x == 0) acc[0] = 0.0;
}

template <int FROM_PARTIALS>
__global__ __launch_bounds__(1024) void gl2_finalize(const double* __restrict__ part,
                                                     float* __restrict__ out) {
    double s = 0.0;
    if (FROM_PARTIALS) {
#pragma unroll
        for (int k = 0; k < NBLK / 1024; ++k)
            s += part[threadIdx.x + k * 1024];
    } else {
        s = (threadIdx.x == 0) ? part[0] : 0.0;
    }
#pragma unroll
    for (int off = 32; off > 0; off >>= 1)
        s += __shfl_down(s, off);

    __shared__ double wsum[16];
    const int lane = threadIdx.x & 63;
    const int wv   = threadIdx.x >> 6;
    if (lane == 0) wsum[wv] = s;
    __syncthreads();
    if (threadIdx.x == 0) {
        double t = 0.0;
#pragma unroll
        for (int w = 0; w < 16; ++w) t += wsum[w];
        out[0] = (float)(t / (double)((size_t)BB * HWSZ));
    }
}

extern "C" void kernel_launch(void* const* d_in, const int* in_sizes, int n_in,
                              void* d_out, int out_size, void* d_ws, size_t ws_size,
                              hipStream_t stream) {
    const float* u   = (const float*)d_in[0];
    const float* psi = (const float*)d_in[1];
    float* out   = (float*)d_out;
    double* ws   = (double*)d_ws;

    // ws_size is constant across calls -> branch is graph-capture safe.
    if (ws_size >= NBLK * sizeof(double)) {
        gl2_main<0><<<NBLK, 256, 0, stream>>>(u, psi, ws);
        gl2_finalize<1><<<1, 1024, 0, stream>>>(ws, out);
    } else {
        gl2_zero_acc<<<1, 64, 0, stream>>>(ws);
        gl2_main<1><<<NBLK, 256, 0, stream>>>(u, psi, ws);
        gl2_finalize<0><<<1, 1024, 0, stream>>>(ws, out);
    }
}

// Round 6
// 271.994 us; speedup vs baseline: 1.0543x; 1.0543x over previous
//
#include <hip/hip_runtime.h>

#define WW 1024
#define HH 1024
#define BB 16
#define HWSZ (HH * WW)
#define NBLK (BB * HH)

typedef float f32x4 __attribute__((ext_vector_type(4)));

// Issue a 16B global load WITHOUT letting the compiler sink/serialize it.
// volatile asm statements keep program order among themselves; the compiler
// inserts no s_waitcnt for them (it thinks asm completes immediately), so all
// issued loads are outstanding together.
#define GLOAD(dst, ptr) \
    asm volatile("global_load_dwordx4 %0, %1, off" : "=v"(dst) : "v"(ptr))

// ---------------------------------------------------------------------------
// D2(f) = gradient(gradient(f)) along one axis (jnp.gradient semantics):
//   i=0:      (f0 - 2 f1 + f2)/2
//   i=1:      (2 f0 - 3 f1 + f3)/4
//   interior: (f[i-2] - 2 f[i] + f[i+2])/4
//   i=N-2:    (f[N-4] - 3 f[N-2] + 2 f[N-1])/4
//   i=N-1:    (f[N-3] - 2 f[N-2] + f[N-1])/2
// ---------------------------------------------------------------------------

__device__ __forceinline__ void lap_compute(const f32x4 vh, const f32x4 vhp,
                                            const f32x4 vhn, const f32x4 vA,
                                            const f32x4 vB, int g,
                                            float cA, float cB, float ch,
                                            float out[4]) {
    float vert[4];
    vert[0] = cA * vA.x + cB * vB.x + ch * vh.x;
    vert[1] = cA * vA.y + cB * vB.y + ch * vh.y;
    vert[2] = cA * vA.z + cB * vB.z + ch * vh.z;
    vert[3] = cA * vA.w + cB * vB.w + ch * vh.w;

    // horizontal: window f[4g-2 .. 4g+5]
    float win[8] = {vhp.z, vhp.w, vh.x, vh.y, vh.z, vh.w, vhn.x, vhn.y};
    float hz[4];
#pragma unroll
    for (int p = 0; p < 4; ++p)
        hz[p] = 0.25f * (win[p] - 2.0f * win[p + 2] + win[p + 4]);

    if (g == 0) {                         // columns 0,1
        hz[0] = 0.5f  * (vh.x - 2.0f * vh.y + vh.z);
        hz[1] = 0.25f * (2.0f * vh.x - 3.0f * vh.y + vh.w);
    } else if (g == WW / 4 - 1) {         // columns W-2, W-1
        hz[2] = 0.25f * (vh.x - 3.0f * vh.z + 2.0f * vh.w);
        hz[3] = 0.5f  * (vh.y - 2.0f * vh.z + vh.w);
    }

#pragma unroll
    for (int p = 0; p < 4; ++p) out[p] = vert[p] + hz[p];
}

// USE_ATOMIC=0: deterministic per-block partials. 1: single f64 atomic.
template <int USE_ATOMIC>
__global__ __launch_bounds__(256) void gl2_main(const float* __restrict__ u,
                                                const float* __restrict__ psi,
                                                double* __restrict__ part) {
    // XCD-aware bijective swizzle (gridDim.x = 16384, divisible by 8)
    const int bid  = blockIdx.x;
    const int work = (bid & 7) * (NBLK >> 3) + (bid >> 3);
    const int b = work >> 10;
    const int h = work & 1023;
    const int g = threadIdx.x;

    int rA, rB; float cA, cB, ch;
    if (h == 0)            { rA = 1;      rB = 2;      cA = -1.0f;  cB = 0.5f;   ch = 0.5f;   }
    else if (h == 1)       { rA = 0;      rB = 3;      cA = 0.5f;   cB = 0.25f;  ch = -0.75f; }
    else if (h == HH - 2)  { rA = HH - 4; rB = HH - 1; cA = 0.25f;  cB = 0.5f;   ch = -0.75f; }
    else if (h == HH - 1)  { rA = HH - 3; rB = HH - 2; cA = 0.5f;   cB = -1.0f;  ch = 0.5f;   }
    else                   { rA = h - 2;  rB = h + 2;  cA = 0.25f;  cB = 0.25f;  ch = -0.5f;  }

    const float* ux = u   + ((size_t)b * 2 + 0) * HWSZ;
    const float* uy = u   + ((size_t)b * 2 + 1) * HWSZ;
    const float* pr = psi + ((size_t)b * 2 + 0) * HWSZ;
    const float* pi = psi + ((size_t)b * 2 + 1) * HWSZ;

    const int gp = (g > 0) ? g - 1 : g;
    const int gn = (g < WW / 4 - 1) ? g + 1 : g;

    // ---- LOAD PHASE: 12 loads issued back-to-back, all outstanding ----
    const f32x4* xrh = (const f32x4*)(ux + (size_t)h * WW);
    const f32x4* yrh = (const f32x4*)(uy + (size_t)h * WW);
    f32x4 xh, xp, xn, xA, xB, yh, yp, yn, yA, yB, r4, i4;
    GLOAD(xh, xrh + g);
    GLOAD(xp, xrh + gp);
    GLOAD(xn, xrh + gn);
    GLOAD(xA, (const f32x4*)(ux + (size_t)rA * WW) + g);
    GLOAD(xB, (const f32x4*)(ux + (size_t)rB * WW) + g);
    GLOAD(yh, yrh + g);
    GLOAD(yp, yrh + gp);
    GLOAD(yn, yrh + gn);
    GLOAD(yA, (const f32x4*)(uy + (size_t)rA * WW) + g);
    GLOAD(yB, (const f32x4*)(uy + (size_t)rB * WW) + g);
    GLOAD(r4, (const f32x4*)(pr + (size_t)h * WW) + g);
    GLOAD(i4, (const f32x4*)(pi + (size_t)h * WW) + g);

    // One wait for all 12. Tying every result as "+v" makes all consumers
    // data-depend on THIS statement -> no compiler pass can hoist compute
    // above the wait (rule #18 hazard closed at every level).
    asm volatile("s_waitcnt vmcnt(0)"
                 : "+v"(xh), "+v"(xp), "+v"(xn), "+v"(xA), "+v"(xB),
                   "+v"(yh), "+v"(yp), "+v"(yn), "+v"(yA), "+v"(yB),
                   "+v"(r4), "+v"(i4));
    __builtin_amdgcn_sched_barrier(0);

    // ---- COMPUTE PHASE ----
    float lapx[4], lapy[4];
    lap_compute(xh, xp, xn, xA, xB, g, cA, cB, ch, lapx);
    lap_compute(yh, yp, yn, yA, yB, g, cA, cB, ch, lapy);

    const float rr[4] = {r4.x, r4.y, r4.z, r4.w};
    const float ii[4] = {i4.x, i4.y, i4.z, i4.w};

    float s = 0.0f;
#pragma unroll
    for (int p = 0; p < 4; ++p) {
        const float c   = 1.0f - (rr[p] * rr[p] + ii[p] * ii[p]);   // 1/eps^2 = 1
        const float lap = lapx[p] + lapy[p];
        const float re  = lap + c * rr[p];
        const float im  = c * ii[p];
        s += re * re + im * im;
    }

#pragma unroll
    for (int off = 32; off > 0; off >>= 1) s += __shfl_down(s, off);

    __shared__ float wsum[4];
    const int lane = threadIdx.x & 63;
    const int wv   = threadIdx.x >> 6;
    if (lane == 0) wsum[wv] = s;
    __syncthreads();
    if (threadIdx.x == 0) {
        const double t = (double)(wsum[0] + wsum[1]) + (double)(wsum[2] + wsum[3]);
        if (USE_ATOMIC) atomicAdd(part, t);
        else            part[bid] = t;
    }
}

__global__ void gl2_zero_acc(double* acc) {
    if (threadIdx.x == 0) acc[0] = 0.0;
}

template <int FROM_PARTIALS>
__global__ __launch_bounds__(1024) void gl2_finalize(const double* __restrict__ part,
                                                     float* __restrict__ out) {
    double s = 0.0;
    if (FROM_PARTIALS) {
#pragma unroll
        for (int k = 0; k < NBLK / 1024; ++k)
            s += part[threadIdx.x + k * 1024];
    } else {
        s = (threadIdx.x == 0) ? part[0] : 0.0;
    }
#pragma unroll
    for (int off = 32; off > 0; off >>= 1)
        s += __shfl_down(s, off);

    __shared__ double wsum[16];
    const int lane = threadIdx.x & 63;
    const int wv   = threadIdx.x >> 6;
    if (lane == 0) wsum[wv] = s;
    __syncthreads();
    if (threadIdx.x == 0) {
        double t = 0.0;
#pragma unroll
        for (int w = 0; w < 16; ++w) t += wsum[w];
        out[0] = (float)(t / (double)((size_t)BB * HWSZ));
    }
}

extern "C" void kernel_launch(void* const* d_in, const int* in_sizes, int n_in,
                              void* d_out, int out_size, void* d_ws, size_t ws_size,
                              hipStream_t stream) {
    const float* u   = (const float*)d_in[0];
    const float* psi = (const float*)d_in[1];
    float* out   = (float*)d_out;
    double* ws   = (double*)d_ws;

    // ws_size is constant across calls -> branch is graph-capture safe.
    if (ws_size >= NBLK * sizeof(double)) {
        gl2_main<0><<<NBLK, 256, 0, stream>>>(u, psi, ws);
        gl2_finalize<1><<<1, 1024, 0, stream>>>(ws, out);
    } else {
        gl2_zero_acc<<<1, 64, 0, stream>>>(ws);
        gl2_main<1><<<NBLK, 256, 0, stream>>>(u, psi, ws);
        gl2_finalize<0><<<1, 1024, 0, stream>>>(ws, out);
    }
}